// Round 1
// baseline (168.463 us; speedup 1.0000x reference)
//
#include <hip/hip_runtime.h>
#include <hip/hip_bf16.h>

typedef __bf16 bf16_t;
typedef bf16_t bf16x4 __attribute__((ext_vector_type(4)));
typedef bf16_t bf16x8 __attribute__((ext_vector_type(8)));
typedef float  f32x4  __attribute__((ext_vector_type(4)));

#define IN_F   1024
#define OUT_F  1024
#define RANK   8
#define NE     8
#define BATCH  32
#define SEQ    1024
#define M_TOT  (BATCH * SEQ)
#define SCALE  0.125f

#define GLOAD_LDS16(g, l)                                                     \
  __builtin_amdgcn_global_load_lds(                                           \
      (const __attribute__((address_space(1))) void*)(g),                     \
      (__attribute__((address_space(3))) void*)(l), 16, 0, 0)

// ---------------------------------------------------------------------------
// Kernel 1: W_eff[e][o][d] = bf16( W[o][d] + SCALE * sum_r Bw[e][o][r]*A[e][r][d] )
// grid: NE*OUT_F blocks (one per (e,o) row), 256 threads, 4 elems/thread.
// ---------------------------------------------------------------------------
__global__ __launch_bounds__(256) void build_weff(
    const float* __restrict__ W, const float* __restrict__ A,
    const float* __restrict__ Bw, bf16_t* __restrict__ weff) {
  const int e  = blockIdx.x >> 10;
  const int o  = blockIdx.x & 1023;
  const int d0 = threadIdx.x << 2;

  f32x4 acc = *(const f32x4*)(W + ((size_t)o << 10) + d0);
  const float* bwr = Bw + (((size_t)e << 10) + o) * RANK;
  const float* ab  = A + (((size_t)e * RANK) << 10) + d0;
#pragma unroll
  for (int r = 0; r < RANK; ++r) {
    const float s = SCALE * bwr[r];
    const f32x4 a4 = *(const f32x4*)(ab + ((size_t)r << 10));
    acc += s * a4;
  }
  bf16x4 ov;
#pragma unroll
  for (int j = 0; j < 4; ++j) ov[j] = (bf16_t)acc[j];
  *(bf16x4*)(weff + (((size_t)e << 10) + o) * IN_F + d0) = ov;
}

// ---------------------------------------------------------------------------
// Kernel 2: x fp32 -> bf16 (grid-stride, float4 in / bf16x4 out)
// ---------------------------------------------------------------------------
__global__ __launch_bounds__(256) void cvt_x(const float* __restrict__ x,
                                             bf16_t* __restrict__ xb, int n4) {
  int i = blockIdx.x * 256 + threadIdx.x;
  const int stride = gridDim.x * 256;
  for (; i < n4; i += stride) {
    const f32x4 v = *(const f32x4*)(x + ((size_t)i << 2));
    bf16x4 o;
#pragma unroll
    for (int j = 0; j < 4; ++j) o[j] = (bf16_t)v[j];
    *(bf16x4*)(xb + ((size_t)i << 2)) = o;
  }
}

// ---------------------------------------------------------------------------
// Kernel 3: out[m][n] = sum_k xb[m][k] * weff[e(m)][n][k] + bias[n]
// m97 structure: 128x128 tile, BK=64, 4 waves (2x2, 64x64 each),
// global_load_lds width-16 staging, 16x16x32 bf16 MFMA, 2 barriers/K-step.
// grid: (M/128)*(N/128) blocks, nb inner for x-panel L2 reuse.
// ---------------------------------------------------------------------------
__global__ __launch_bounds__(256) void gemm_weff(
    const bf16_t* __restrict__ xb, const bf16_t* __restrict__ weff,
    const float* __restrict__ bias, const int* __restrict__ sid,
    float* __restrict__ out) {
  __shared__ bf16_t As[128 * 64];
  __shared__ bf16_t Bs[128 * 64];

  const int bid = blockIdx.x;
  const int mb = bid >> 3;     // 256 m-blocks
  const int nb = bid & 7;      // 8 n-blocks (inner: share x panel)
  const int m0 = mb << 7, n0 = nb << 7;
  const int e = sid[mb >> 3];  // batch = m0/1024 = mb/8
  const bf16_t* wp = weff + ((size_t)e << 20);

  const int tid = threadIdx.x;
  const int lane = tid & 63, wid = tid >> 6;
  const int wm = wid >> 1, wn = wid & 1;          // 2x2 wave grid
  const int srow = tid >> 3, scol = (tid & 7) << 3;  // staging: row t/8, col (t%8)*8

  const bf16_t* ag = xb + (((size_t)(m0 + srow)) << 10) + scol;
  const bf16_t* bg = wp + (((size_t)(n0 + srow)) << 10) + scol;
  bf16_t* asd = As + tid * 8;   // linear LDS dest: wave-uniform base + lane*16B
  bf16_t* bsd = Bs + tid * 8;

  const int fr = lane & 15;            // fragment row/col within 16
  const int fk = (lane >> 4) << 3;     // k sub-offset (8 per quarter-wave)

  f32x4 acc[4][4] = {};

  for (int kt = 0; kt < 16; ++kt) {
#pragma unroll
    for (int i = 0; i < 4; ++i) {
      GLOAD_LDS16(ag + (i << 15), asd + (i << 11));  // +32 rows / iter
      GLOAD_LDS16(bg + (i << 15), bsd + (i << 11));
    }
    ag += 64; bg += 64;
    __syncthreads();  // drains vmcnt -> staged data visible
#pragma unroll
    for (int kk = 0; kk < 2; ++kk) {
      bf16x8 af[4], bfr[4];
#pragma unroll
      for (int mi = 0; mi < 4; ++mi)
        af[mi] = *(const bf16x8*)(As + ((wm << 6) + (mi << 4) + fr) * 64 +
                                  (kk << 5) + fk);
#pragma unroll
      for (int ni = 0; ni < 4; ++ni)
        bfr[ni] = *(const bf16x8*)(Bs + ((wn << 6) + (ni << 4) + fr) * 64 +
                                   (kk << 5) + fk);
#pragma unroll
      for (int mi = 0; mi < 4; ++mi)
#pragma unroll
        for (int ni = 0; ni < 4; ++ni)
          acc[mi][ni] = __builtin_amdgcn_mfma_f32_16x16x32_bf16(
              af[mi], bfr[ni], acc[mi][ni], 0, 0, 0);
    }
    __syncthreads();
  }

  // epilogue: C/D layout col=lane&15, row=(lane>>4)*4+j
  const int crow = (lane >> 4) << 2;
#pragma unroll
  for (int ni = 0; ni < 4; ++ni) {
    const int col = n0 + (wn << 6) + (ni << 4) + fr;
    const float bv = bias[col];
#pragma unroll
    for (int mi = 0; mi < 4; ++mi) {
      const int row = m0 + (wm << 6) + (mi << 4) + crow;
#pragma unroll
      for (int j = 0; j < 4; ++j)
        out[((size_t)(row + j) << 10) + col] = acc[mi][ni][j] + bv;
    }
  }
}

// ---------------------------------------------------------------------------
// Fallback (ws too small): naive fp32, correct but slow.
// ---------------------------------------------------------------------------
__global__ __launch_bounds__(256) void lora_naive(
    const float* __restrict__ x, const float* __restrict__ W,
    const float* __restrict__ bias, const float* __restrict__ A,
    const float* __restrict__ Bw, const int* __restrict__ sid,
    float* __restrict__ out) {
  const int m = blockIdx.x;
  const int e = sid[m >> 10];
  __shared__ float xs[IN_F];
  __shared__ float h[RANK];
  const int tid = threadIdx.x;
  for (int i = tid; i < IN_F; i += 256) xs[i] = x[((size_t)m << 10) + i];
  __syncthreads();
  if (tid < RANK) {
    float s = 0.f;
    const float* ar = A + (((size_t)e * RANK + tid) << 10);
    for (int d = 0; d < IN_F; ++d) s += xs[d] * ar[d];
    h[tid] = s * SCALE;
  }
  __syncthreads();
  for (int o = tid; o < OUT_F; o += 256) {
    const float* wr = W + ((size_t)o << 10);
    float s = 0.f;
    for (int d = 0; d < IN_F; ++d) s += xs[d] * wr[d];
    const float* bwr = Bw + (((size_t)e << 10) + o) * RANK;
    float l = 0.f;
#pragma unroll
    for (int r = 0; r < RANK; ++r) l += h[r] * bwr[r];
    out[((size_t)m << 10) + o] = s + bias[o] + l;
  }
}

extern "C" void kernel_launch(void* const* d_in, const int* in_sizes, int n_in,
                              void* d_out, int out_size, void* d_ws,
                              size_t ws_size, hipStream_t stream) {
  const float* x   = (const float*)d_in[0];
  const float* W   = (const float*)d_in[1];
  const float* b   = (const float*)d_in[2];
  const float* A   = (const float*)d_in[3];
  const float* Bw  = (const float*)d_in[4];
  const int*   sid = (const int*)d_in[5];
  float* out = (float*)d_out;

  const size_t weff_bytes = (size_t)NE * OUT_F * IN_F * 2;  // 16 MiB
  const size_t xb_bytes   = (size_t)M_TOT * IN_F * 2;       // 64 MiB

  if (ws_size >= weff_bytes + xb_bytes) {
    bf16_t* weff = (bf16_t*)d_ws;
    bf16_t* xb   = (bf16_t*)((char*)d_ws + weff_bytes);
    hipLaunchKernelGGL(build_weff, dim3(NE * OUT_F), dim3(256), 0, stream,
                       W, A, Bw, weff);
    hipLaunchKernelGGL(cvt_x, dim3(4096), dim3(256), 0, stream,
                       x, xb, M_TOT * IN_F / 4);
    hipLaunchKernelGGL(gemm_weff, dim3((M_TOT / 128) * (OUT_F / 128)),
                       dim3(256), 0, stream, xb, weff, b, sid, out);
  } else {
    hipLaunchKernelGGL(lora_naive, dim3(M_TOT), dim3(256), 0, stream,
                       x, W, b, A, Bw, sid, out);
  }
}

// Round 2
// 139.311 us; speedup vs baseline: 1.2093x; 1.2093x over previous
//
#include <hip/hip_runtime.h>
#include <hip/hip_bf16.h>

typedef __bf16 bf16_t;
typedef bf16_t bf16x4 __attribute__((ext_vector_type(4)));
typedef bf16_t bf16x8 __attribute__((ext_vector_type(8)));
typedef float  f32x4  __attribute__((ext_vector_type(4)));

#define IN_F   1024
#define OUT_F  1024
#define RANK   8
#define NE     8
#define BATCH  32
#define SEQ    1024
#define M_TOT  (BATCH * SEQ)
#define SCALE  0.125f
#define NT     16   // K / 64

#define GLOAD_LDS16(g, l)                                                     \
  __builtin_amdgcn_global_load_lds(                                           \
      (const __attribute__((address_space(1))) void*)(g),                     \
      (__attribute__((address_space(3))) void*)(l), 16, 0, 0)

#define CFENCE asm volatile("" ::: "memory")
#define BAR()                                                                 \
  do { CFENCE; __builtin_amdgcn_s_barrier(); CFENCE; } while (0)
#define VMCNT(n) asm volatile("s_waitcnt vmcnt(" #n ")" ::: "memory")

// ---------------------------------------------------------------------------
// Kernel 1: W_eff[e][o][d] = bf16( W[o][d] + SCALE * sum_r Bw[e][o][r]*A[e][r][d] )
// ---------------------------------------------------------------------------
__global__ __launch_bounds__(256) void build_weff(
    const float* __restrict__ W, const float* __restrict__ A,
    const float* __restrict__ Bw, bf16_t* __restrict__ weff) {
  const int e  = blockIdx.x >> 10;
  const int o  = blockIdx.x & 1023;
  const int d0 = threadIdx.x << 2;

  f32x4 acc = *(const f32x4*)(W + ((size_t)o << 10) + d0);
  const float* bwr = Bw + (((size_t)e << 10) + o) * RANK;
  const float* ab  = A + (((size_t)e * RANK) << 10) + d0;
#pragma unroll
  for (int r = 0; r < RANK; ++r) {
    const float s = SCALE * bwr[r];
    const f32x4 a4 = *(const f32x4*)(ab + ((size_t)r << 10));
    acc += s * a4;
  }
  bf16x4 ov;
#pragma unroll
  for (int j = 0; j < 4; ++j) ov[j] = (bf16_t)acc[j];
  *(bf16x4*)(weff + (((size_t)e << 10) + o) * IN_F + d0) = ov;
}

// ---------------------------------------------------------------------------
// Kernel 2: x fp32 -> bf16
// ---------------------------------------------------------------------------
__global__ __launch_bounds__(256) void cvt_x(const float* __restrict__ x,
                                             bf16_t* __restrict__ xb, int n4) {
  int i = blockIdx.x * 256 + threadIdx.x;
  const int stride = gridDim.x * 256;
  for (; i < n4; i += stride) {
    const f32x4 v = *(const f32x4*)(x + ((size_t)i << 2));
    bf16x4 o;
#pragma unroll
    for (int j = 0; j < 4; ++j) o[j] = (bf16_t)v[j];
    *(bf16x4*)(xb + ((size_t)i << 2)) = o;
  }
}

// ---------------------------------------------------------------------------
// Kernel 3: 256x256 tile, BK=64, 8 waves (2M x 4N), deep pipeline:
// per phase (=one kstep): 12 ds_read_b128 -> stage one A+B K-half (4
// global_load_lds) -> counted vmcnt(4) once per K-tile -> barrier -> 32 MFMA.
// LDS: [buf2][A/B][khalf2][256x32 bf16], granule-XOR swizzle ((r>>1)&3)
// applied on pre-swizzled global source AND on ds_read address.
// ---------------------------------------------------------------------------
__global__ __launch_bounds__(512, 2) void gemm256(
    const bf16_t* __restrict__ xb, const bf16_t* __restrict__ weff,
    const float* __restrict__ bias, const int* __restrict__ sid,
    float* __restrict__ out) {
  __shared__ bf16_t lds[2][2][2][8192];  // 128 KiB

  const int bid0 = blockIdx.x;
  const int wgid = ((bid0 & 7) << 6) + (bid0 >> 3);  // XCD chunked (512 wgs)
  const int mb = wgid >> 2, nb = wgid & 3;
  const int m0 = mb << 8, n0 = nb << 8;
  const int e = sid[mb >> 2];

  const int tid = threadIdx.x;
  const int lane = tid & 63, wid = tid >> 6;
  const int wm = wid >> 2, wn = wid & 3;

  const bf16_t* agbase = xb + ((size_t)m0 << 10);
  const bf16_t* bgbase = weff + ((size_t)e << 20) + ((size_t)n0 << 10);

  // staging: instr i covers LDS bytes wid*2048 + i*1024 + lane*16 (linear),
  // i.e. row r = wid*32 + i*16 + (lane>>2), granule lane&3. Source granule is
  // pre-swizzled: sg = (lane&3) ^ ((r>>1)&3).
  int soff[2];
#pragma unroll
  for (int i = 0; i < 2; ++i) {
    const int r = (wid << 5) + (i << 4) + (lane >> 2);
    const int sg = (lane & 3) ^ ((r >> 1) & 3);
    soff[i] = (r << 10) + (sg << 3);  // elements into [256][1024] source
  }

  // read offsets (elements within one [256][32] khalf tile)
  int aoff[8], boff[4];
#pragma unroll
  for (int mi = 0; mi < 8; ++mi) {
    const int r = (wm << 7) + (mi << 4) + (lane & 15);
    const int g = (lane >> 4) ^ ((r >> 1) & 3);
    aoff[mi] = (r << 5) + (g << 3);
  }
#pragma unroll
  for (int ni = 0; ni < 4; ++ni) {
    const int r = (wn << 6) + (ni << 4) + (lane & 15);
    const int g = (lane >> 4) ^ ((r >> 1) & 3);
    boff[ni] = (r << 5) + (g << 3);
  }

  f32x4 acc[8][4] = {};

#define STAGE(gbase, mat, kt, kh)                                             \
  do {                                                                        \
    bf16_t* _d = &lds[(kt) & 1][mat][kh][wid << 10];                          \
    const int _kc = ((kt) << 6) + ((kh) << 5);                                \
    GLOAD_LDS16((gbase) + _kc + soff[0], _d);                                 \
    GLOAD_LDS16((gbase) + _kc + soff[1], _d + 512);                           \
  } while (0)

#define PHASE_READS(kt, kh)                                                   \
  do {                                                                        \
    const bf16_t* _ab = &lds[(kt) & 1][0][kh][0];                             \
    const bf16_t* _bb = &lds[(kt) & 1][1][kh][0];                             \
    _Pragma("unroll") for (int mi = 0; mi < 8; ++mi)                          \
        af[mi] = *(const bf16x8*)(_ab + aoff[mi]);                            \
    _Pragma("unroll") for (int ni = 0; ni < 4; ++ni)                          \
        bfr[ni] = *(const bf16x8*)(_bb + boff[ni]);                           \
  } while (0)

#define MFMAS()                                                               \
  do {                                                                        \
    __builtin_amdgcn_s_setprio(1);                                            \
    _Pragma("unroll") for (int mi = 0; mi < 8; ++mi)                          \
        _Pragma("unroll") for (int ni = 0; ni < 4; ++ni)                      \
            acc[mi][ni] = __builtin_amdgcn_mfma_f32_16x16x32_bf16(            \
                af[mi], bfr[ni], acc[mi][ni], 0, 0, 0);                       \
    __builtin_amdgcn_s_setprio(0);                                            \
  } while (0)

  // prologue: tile0 (kh0,kh1) + tile1 kh0 in flight; retire tile0
  STAGE(agbase, 0, 0, 0); STAGE(bgbase, 1, 0, 0);
  STAGE(agbase, 0, 0, 1); STAGE(bgbase, 1, 0, 1);
  STAGE(agbase, 0, 1, 0); STAGE(bgbase, 1, 1, 0);
  VMCNT(4);
  BAR();

  bf16x8 af[8], bfr[4];
  for (int j = 0; j < NT - 2; ++j) {
    // phase ks0: compute tile j kh0; stage kh1(j+1) (other buf, freed)
    PHASE_READS(j, 0);
    STAGE(agbase, 0, j + 1, 1); STAGE(bgbase, 1, j + 1, 1);
    BAR();
    MFMAS();
    BAR();
    // phase ks1: compute tile j kh1; stage kh0(j+2) (this buf's kh0, freed);
    // vmcnt(4) retires tile j+1 exactly, leaves kh0(j+2) in flight.
    PHASE_READS(j, 1);
    STAGE(agbase, 0, j + 2, 0); STAGE(bgbase, 1, j + 2, 0);
    VMCNT(4);
    BAR();
    MFMAS();
    BAR();
  }
  // tile NT-2: stage last half, then drain
  PHASE_READS(NT - 2, 0);
  STAGE(agbase, 0, NT - 1, 1); STAGE(bgbase, 1, NT - 1, 1);
  BAR();
  MFMAS();
  BAR();
  PHASE_READS(NT - 2, 1);
  VMCNT(0);
  BAR();
  MFMAS();
  BAR();
  // tile NT-1: all resident, no staging
  PHASE_READS(NT - 1, 0);
  MFMAS();
  PHASE_READS(NT - 1, 1);
  MFMAS();

  // epilogue: C/D layout col=lane&15, row=(lane>>4)*4+j
  const int R0 = m0 + (wm << 7);
  const int C0 = n0 + (wn << 6);
  const int crow = (lane >> 4) << 2;
  const int ccol = lane & 15;
#pragma unroll
  for (int ni = 0; ni < 4; ++ni) {
    const int col = C0 + (ni << 4) + ccol;
    const float bv = bias[col];
#pragma unroll
    for (int mi = 0; mi < 8; ++mi) {
      const int row = R0 + (mi << 4) + crow;
#pragma unroll
      for (int j2 = 0; j2 < 4; ++j2)
        out[((size_t)(row + j2) << 10) + col] = acc[mi][ni][j2] + bv;
    }
  }
#undef STAGE
#undef PHASE_READS
#undef MFMAS
}

// ---------------------------------------------------------------------------
// Fallback (ws too small): naive fp32.
// ---------------------------------------------------------------------------
__global__ __launch_bounds__(256) void lora_naive(
    const float* __restrict__ x, const float* __restrict__ W,
    const float* __restrict__ bias, const float* __restrict__ A,
    const float* __restrict__ Bw, const int* __restrict__ sid,
    float* __restrict__ out) {
  const int m = blockIdx.x;
  const int e = sid[m >> 10];
  __shared__ float xs[IN_F];
  __shared__ float h[RANK];
  const int tid = threadIdx.x;
  for (int i = tid; i < IN_F; i += 256) xs[i] = x[((size_t)m << 10) + i];
  __syncthreads();
  if (tid < RANK) {
    float s = 0.f;
    const float* ar = A + (((size_t)e * RANK + tid) << 10);
    for (int d = 0; d < IN_F; ++d) s += xs[d] * ar[d];
    h[tid] = s * SCALE;
  }
  __syncthreads();
  for (int o = tid; o < OUT_F; o += 256) {
    const float* wr = W + ((size_t)o << 10);
    float s = 0.f;
    for (int d = 0; d < IN_F; ++d) s += xs[d] * wr[d];
    const float* bwr = Bw + (((size_t)e << 10) + o) * RANK;
    float l = 0.f;
#pragma unroll
    for (int r = 0; r < RANK; ++r) l += h[r] * bwr[r];
    out[((size_t)m << 10) + o] = s + bias[o] + l;
  }
}

extern "C" void kernel_launch(void* const* d_in, const int* in_sizes, int n_in,
                              void* d_out, int out_size, void* d_ws,
                              size_t ws_size, hipStream_t stream) {
  const float* x   = (const float*)d_in[0];
  const float* W   = (const float*)d_in[1];
  const float* b   = (const float*)d_in[2];
  const float* A   = (const float*)d_in[3];
  const float* Bw  = (const float*)d_in[4];
  const int*   sid = (const int*)d_in[5];
  float* out = (float*)d_out;

  const size_t weff_bytes = (size_t)NE * OUT_F * IN_F * 2;  // 16 MiB
  const size_t xb_bytes   = (size_t)M_TOT * IN_F * 2;       // 64 MiB

  if (ws_size >= weff_bytes + xb_bytes) {
    bf16_t* weff = (bf16_t*)d_ws;
    bf16_t* xb   = (bf16_t*)((char*)d_ws + weff_bytes);
    hipLaunchKernelGGL(build_weff, dim3(NE * OUT_F), dim3(256), 0, stream,
                       W, A, Bw, weff);
    hipLaunchKernelGGL(cvt_x, dim3(4096), dim3(256), 0, stream,
                       x, xb, M_TOT * IN_F / 4);
    hipLaunchKernelGGL(gemm256, dim3((M_TOT / 256) * (OUT_F / 256)),
                       dim3(512), 0, stream, xb, weff, b, sid, out);
  } else {
    hipLaunchKernelGGL(lora_naive, dim3(M_TOT), dim3(256), 0, stream,
                       x, W, b, A, Bw, sid, out);
  }
}

// Round 3
// 119.788 us; speedup vs baseline: 1.4063x; 1.1630x over previous
//
#include <hip/hip_runtime.h>
#include <hip/hip_bf16.h>

typedef __bf16 bf16_t;
typedef bf16_t bf16x4 __attribute__((ext_vector_type(4)));
typedef bf16_t bf16x8 __attribute__((ext_vector_type(8)));
typedef float  f32x4  __attribute__((ext_vector_type(4)));

#define IN_F   1024
#define OUT_F  1024
#define RANK   8
#define NE     8
#define BATCH  32
#define SEQ    1024
#define M_TOT  (BATCH * SEQ)
#define SCALE  0.125f
#define NT     16   // K / 64

#define GLOAD_LDS16(g, l)                                                     \
  __builtin_amdgcn_global_load_lds(                                           \
      (const __attribute__((address_space(1))) void*)(g),                     \
      (__attribute__((address_space(3))) void*)(l), 16, 0, 0)

#define CFENCE asm volatile("" ::: "memory")
#define BAR()                                                                 \
  do { CFENCE; __builtin_amdgcn_s_barrier(); CFENCE; } while (0)
#define VMCNT(n) asm volatile("s_waitcnt vmcnt(" #n ")" ::: "memory")
#define LGKM0()  asm volatile("s_waitcnt lgkmcnt(0)" ::: "memory")

// ---------------------------------------------------------------------------
// Kernel 1: W_eff[e][o][d] = bf16( W[o][d] + SCALE * sum_r Bw[e][o][r]*A[e][r][d] )
// ---------------------------------------------------------------------------
__global__ __launch_bounds__(256) void build_weff(
    const float* __restrict__ W, const float* __restrict__ A,
    const float* __restrict__ Bw, bf16_t* __restrict__ weff) {
  const int e  = blockIdx.x >> 10;
  const int o  = blockIdx.x & 1023;
  const int d0 = threadIdx.x << 2;

  f32x4 acc = *(const f32x4*)(W + ((size_t)o << 10) + d0);
  const float* bwr = Bw + (((size_t)e << 10) + o) * RANK;
  const float* ab  = A + (((size_t)e * RANK) << 10) + d0;
#pragma unroll
  for (int r = 0; r < RANK; ++r) {
    const float s = SCALE * bwr[r];
    const f32x4 a4 = *(const f32x4*)(ab + ((size_t)r << 10));
    acc += s * a4;
  }
  bf16x4 ov;
#pragma unroll
  for (int j = 0; j < 4; ++j) ov[j] = (bf16_t)acc[j];
  *(bf16x4*)(weff + (((size_t)e << 10) + o) * IN_F + d0) = ov;
}

// ---------------------------------------------------------------------------
// Kernel 2 (fused): 256x256 tile, BK=64, 8 waves. A-operand: x fp32 read
// direct from global -> regs -> cvt_pk bf16 -> swizzled ds_write (T14).
// B-operand: weff bf16 via global_load_lds with pre-swizzled source.
// Counted-vmcnt ledger (per iter): ks0 implicit vmcnt(2) for A-regs;
// ks1 VMCNT(2) keeps only bh0(j+2) in flight across the barrier.
// ---------------------------------------------------------------------------
__global__ __launch_bounds__(512, 2) void gemm_fused(
    const float* __restrict__ xf, const bf16_t* __restrict__ weff,
    const float* __restrict__ bias, const int* __restrict__ sid,
    float* __restrict__ out) {
  __shared__ bf16_t lds[2][2][2][8192];  // [buf][A/B][kh][256x32] = 128 KiB

  const int bid0 = blockIdx.x;
  const int wgid = ((bid0 & 7) << 6) + (bid0 >> 3);  // XCD chunked (512 wgs)
  const int mb = wgid >> 2, nb = wgid & 3;
  const int m0 = mb << 8, n0 = nb << 8;
  const int e = sid[mb >> 2];

  const int tid = threadIdx.x;
  const int lane = tid & 63, wid = tid >> 6;
  const int wm = wid >> 2, wn = wid & 3;

  const float*  agf   = xf + ((size_t)m0 << 10);
  const bf16_t* bgbase = weff + ((size_t)e << 20) + ((size_t)n0 << 10);

  // ---- B staging (gload_lds, pre-swizzled source granule) ----
  int soff[2];
#pragma unroll
  for (int i = 0; i < 2; ++i) {
    const int r = (wid << 5) + (i << 4) + (lane >> 2);
    const int sg = (lane & 3) ^ ((r >> 1) & 3);
    soff[i] = (r << 10) + (sg << 3);
  }

  // ---- A reg-staging: 4 runs of 8 f32 (row r=q*64+tid/8, cols (tid%8)*8..+8)
  int agoff[4], awoff[4];
  {
    const int c0 = (tid & 7) << 3;          // 0..56 within 64-wide k-tile
    const int kh = c0 >> 5;                 // which k-half
    const int cg = (c0 >> 3) & 3;           // granule within half
#pragma unroll
    for (int q = 0; q < 4; ++q) {
      const int r = (q << 6) + (tid >> 3);
      agoff[q] = (r << 10) + c0;
      const int gs = cg ^ ((r >> 1) & 3);   // write-side swizzle
      awoff[q] = (kh << 13) + (r << 5) + (gs << 3);
    }
  }

  // ---- fragment read offsets (swizzled), within one [256][32] kh tile ----
  int aoff[8], boff[4];
#pragma unroll
  for (int mi = 0; mi < 8; ++mi) {
    const int r = (wm << 7) + (mi << 4) + (lane & 15);
    const int g = (lane >> 4) ^ ((r >> 1) & 3);
    aoff[mi] = (r << 5) + (g << 3);
  }
#pragma unroll
  for (int ni = 0; ni < 4; ++ni) {
    const int r = (wn << 6) + (ni << 4) + (lane & 15);
    const int g = (lane >> 4) ^ ((r >> 1) & 3);
    boff[ni] = (r << 5) + (g << 3);
  }

  f32x4 acc[8][4] = {};
  f32x4 ar[8];

#define A_ISSUE(kt)                                                           \
  do {                                                                        \
    const float* _x = agf + ((kt) << 6);                                      \
    _Pragma("unroll") for (int q = 0; q < 4; ++q) {                           \
      ar[2 * q]     = *(const f32x4*)(_x + agoff[q]);                         \
      ar[2 * q + 1] = *(const f32x4*)(_x + agoff[q] + 4);                     \
    }                                                                         \
  } while (0)

#define A_WRITE(kt)                                                           \
  do {                                                                        \
    bf16_t* _ab = &lds[(kt) & 1][0][0][0];                                    \
    _Pragma("unroll") for (int q = 0; q < 4; ++q) {                           \
      bf16x8 v;                                                               \
      _Pragma("unroll") for (int i2 = 0; i2 < 4; ++i2) {                      \
        v[i2]     = (bf16_t)ar[2 * q][i2];                                    \
        v[4 + i2] = (bf16_t)ar[2 * q + 1][i2];                                \
      }                                                                       \
      *(bf16x8*)(_ab + awoff[q]) = v;                                         \
    }                                                                         \
  } while (0)

#define BSTAGE(kt, kh)                                                        \
  do {                                                                        \
    bf16_t* _d = &lds[(kt) & 1][1][kh][wid << 10];                            \
    const int _kc = ((kt) << 6) + ((kh) << 5);                                \
    GLOAD_LDS16(bgbase + _kc + soff[0], _d);                                  \
    GLOAD_LDS16(bgbase + _kc + soff[1], _d + 512);                            \
  } while (0)

#define PHASE_READS(kt, kh)                                                   \
  do {                                                                        \
    const bf16_t* _ab = &lds[(kt) & 1][0][kh][0];                             \
    const bf16_t* _bb = &lds[(kt) & 1][1][kh][0];                             \
    _Pragma("unroll") for (int mi = 0; mi < 8; ++mi)                          \
        af[mi] = *(const bf16x8*)(_ab + aoff[mi]);                            \
    _Pragma("unroll") for (int ni = 0; ni < 4; ++ni)                          \
        bfr[ni] = *(const bf16x8*)(_bb + boff[ni]);                           \
  } while (0)

#define MFMAS()                                                               \
  do {                                                                        \
    __builtin_amdgcn_s_setprio(1);                                            \
    _Pragma("unroll") for (int mi = 0; mi < 8; ++mi)                          \
        _Pragma("unroll") for (int ni = 0; ni < 4; ++ni)                      \
            acc[mi][ni] = __builtin_amdgcn_mfma_f32_16x16x32_bf16(            \
                af[mi], bfr[ni], acc[mi][ni], 0, 0, 0);                       \
    __builtin_amdgcn_s_setprio(0);                                            \
  } while (0)

  // -------- prologue: publish tile 0; leave a_1 + bh0_1 in flight --------
  A_ISSUE(0);                 // 8 vm (reg)
  BSTAGE(0, 0); BSTAGE(0, 1); // 4 vm
  A_WRITE(0);                 // implicit vmcnt(4): a_0 done, B0 in flight
  A_ISSUE(1);                 // 8 vm
  BSTAGE(1, 0);               // 2 vm
  VMCNT(10);                  // retire B0; keep a_1(8)+bh0_1(2)
  LGKM0();                    // A0 ds_writes visible
  BAR();

  bf16x8 af[8], bfr[4];
  for (int j = 0; j < NT - 2; ++j) {
    // ks0: compute (j,kh0); write A(j+1); issue a(j+2); stage B(j+1,kh1)
    PHASE_READS(j, 0);
    A_WRITE(j + 1);           // implicit vmcnt(2): a_{j+1} done, bh0_{j+1} kept
    A_ISSUE(j + 2);
    BSTAGE(j + 1, 1);
    BAR();
    MFMAS();
    BAR();
    // ks1: compute (j,kh1); stage B(j+2,kh0) into freed kh0 of this buf
    PHASE_READS(j, 1);
    BSTAGE(j + 2, 0);
    VMCNT(2);                 // keep only bh0_{j+2}; retires bh1_{j+1}, a_{j+2}
    LGKM0();                  // publish A(j+1) ds_writes
    BAR();
    MFMAS();
    BAR();
  }
  // -------- tail: tile NT-2 (stage last B half + A already in regs) --------
  PHASE_READS(NT - 2, 0);
  A_WRITE(NT - 1);
  BSTAGE(NT - 1, 1);
  BAR();
  MFMAS();
  BAR();
  PHASE_READS(NT - 2, 1);
  VMCNT(0);
  LGKM0();
  BAR();
  MFMAS();
  BAR();
  // -------- tile NT-1: fully resident --------
  PHASE_READS(NT - 1, 0);
  MFMAS();
  PHASE_READS(NT - 1, 1);
  MFMAS();

  // epilogue: C/D layout col=lane&15, row=(lane>>4)*4+j
  const int R0 = m0 + (wm << 7);
  const int C0 = n0 + (wn << 6);
  const int crow = (lane >> 4) << 2;
  const int ccol = lane & 15;
#pragma unroll
  for (int ni = 0; ni < 4; ++ni) {
    const int col = C0 + (ni << 4) + ccol;
    const float bv = bias[col];
#pragma unroll
    for (int mi = 0; mi < 8; ++mi) {
      const int row = R0 + (mi << 4) + crow;
#pragma unroll
      for (int j2 = 0; j2 < 4; ++j2)
        out[((size_t)(row + j2) << 10) + col] = acc[mi][ni][j2] + bv;
    }
  }
#undef A_ISSUE
#undef A_WRITE
#undef BSTAGE
#undef PHASE_READS
#undef MFMAS
}

// ---------------------------------------------------------------------------
// Fallback (ws too small): naive fp32.
// ---------------------------------------------------------------------------
__global__ __launch_bounds__(256) void lora_naive(
    const float* __restrict__ x, const float* __restrict__ W,
    const float* __restrict__ bias, const float* __restrict__ A,
    const float* __restrict__ Bw, const int* __restrict__ sid,
    float* __restrict__ out) {
  const int m = blockIdx.x;
  const int e = sid[m >> 10];
  __shared__ float xs[IN_F];
  __shared__ float h[RANK];
  const int tid = threadIdx.x;
  for (int i = tid; i < IN_F; i += 256) xs[i] = x[((size_t)m << 10) + i];
  __syncthreads();
  if (tid < RANK) {
    float s = 0.f;
    const float* ar = A + (((size_t)e * RANK + tid) << 10);
    for (int d = 0; d < IN_F; ++d) s += xs[d] * ar[d];
    h[tid] = s * SCALE;
  }
  __syncthreads();
  for (int o = tid; o < OUT_F; o += 256) {
    const float* wr = W + ((size_t)o << 10);
    float s = 0.f;
    for (int d = 0; d < IN_F; ++d) s += xs[d] * wr[d];
    const float* bwr = Bw + (((size_t)e << 10) + o) * RANK;
    float l = 0.f;
#pragma unroll
    for (int r = 0; r < RANK; ++r) l += h[r] * bwr[r];
    out[((size_t)m << 10) + o] = s + bias[o] + l;
  }
}

extern "C" void kernel_launch(void* const* d_in, const int* in_sizes, int n_in,
                              void* d_out, int out_size, void* d_ws,
                              size_t ws_size, hipStream_t stream) {
  const float* x   = (const float*)d_in[0];
  const float* W   = (const float*)d_in[1];
  const float* b   = (const float*)d_in[2];
  const float* A   = (const float*)d_in[3];
  const float* Bw  = (const float*)d_in[4];
  const int*   sid = (const int*)d_in[5];
  float* out = (float*)d_out;

  const size_t weff_bytes = (size_t)NE * OUT_F * IN_F * 2;  // 16 MiB

  if (ws_size >= weff_bytes) {
    bf16_t* weff = (bf16_t*)d_ws;
    hipLaunchKernelGGL(build_weff, dim3(NE * OUT_F), dim3(256), 0, stream,
                       W, A, Bw, weff);
    hipLaunchKernelGGL(gemm_fused, dim3((M_TOT / 256) * (OUT_F / 256)),
                       dim3(512), 0, stream, x, weff, b, sid, out);
  } else {
    hipLaunchKernelGGL(lora_naive, dim3(M_TOT), dim3(256), 0, stream,
                       x, W, b, A, Bw, sid, out);
  }
}